// Round 3
// baseline (295.193 us; speedup 1.0000x reference)
//
#include <hip/hip_runtime.h>
#include <math.h>

typedef __attribute__((ext_vector_type(8))) __bf16 bf16x8;
typedef __attribute__((ext_vector_type(4))) __bf16 bf16x4;
typedef __attribute__((ext_vector_type(4))) float floatx4;

__device__ __forceinline__ float fast_rcp(float x) { return __builtin_amdgcn_rcpf(x); }
__device__ __forceinline__ float sigmoidf_(float z) { return fast_rcp(1.0f + __expf(-z)); }
__device__ __forceinline__ float fast_tanh(float z) {
    float e = __expf(2.0f * z);
    return 1.0f - 2.0f * fast_rcp(e + 1.0f);
}
__device__ __forceinline__ float leaky(float v) { return fmaxf(v, 0.01f * v); }

// ---- grid fp32 -> bf16 conversion into workspace ----
__global__ void convert_grids(const float* __restrict__ g0, const float* __restrict__ g1,
                              __bf16* __restrict__ o0, __bf16* __restrict__ o1, int elems) {
    int i = blockIdx.x * blockDim.x + threadIdx.x;
    int nvec = elems >> 2;
    if (i < nvec) {
        float4 v = ((const float4*)g0)[i];
        bf16x4 r = { (__bf16)v.x, (__bf16)v.y, (__bf16)v.z, (__bf16)v.w };
        ((bf16x4*)o0)[i] = r;
    } else if (i < 2 * nvec) {
        int j = i - nvec;
        float4 v = ((const float4*)g1)[j];
        bf16x4 r = { (__bf16)v.x, (__bf16)v.y, (__bf16)v.z, (__bf16)v.w };
        ((bf16x4*)o1)[j] = r;
    }
}

#define XSTR 72   // X/h1 row stride in bf16 elems (144 B: 16B-aligned rows)

// 32 points per wave; lane = (pass = lane>>5, point = lane&31).
// fc1: D[out][pt] = W1[out][k] * X[pt][k]^T via mfma(A=W1,B=X) -> writeback is
// 4 consecutive feats per reg quad -> ds_write_b64. fc2 likewise -> b128.
// All cross-lane exchange is intra-wave (per-wave LDS region, lgkmcnt fences only).
template<bool BF16G>
__global__ __launch_bounds__(256, 5) void gridnet_fwd(
    const float2* __restrict__ pos, const float2* __restrict__ dir_,
    const float* __restrict__ pos_gridf, const float* __restrict__ dir_gridf,
    const __bf16* __restrict__ pos_gridb, const __bf16* __restrict__ dir_gridb,
    const float* __restrict__ enc_w1, const float* __restrict__ enc_b1,
    const float* __restrict__ enc_w2, const float* __restrict__ enc_b2,
    const float* __restrict__ fc_w1, const float* __restrict__ fc_b1,
    const float* __restrict__ fc_w2, const float* __restrict__ fc_b2,
    const float* __restrict__ fc_w3, const float* __restrict__ fc_b3,
    const float* __restrict__ fc_w4, const float* __restrict__ fc_b4,
    float* __restrict__ out, int n)
{
    __shared__ __align__(16) __bf16 smem[4*32*XSTR + 64*XSTR + 16*XSTR];
    __shared__ float b1lds[64];
    __shared__ float b2lds[16];

    const int tid  = threadIdx.x;
    const int lane = tid & 63;
    const int wid  = tid >> 6;
    const int quad = lane >> 4;
    const int l15  = lane & 15;
    const int hp   = lane >> 5;   // 0 = pos pass, 1 = dir pass
    const int p32  = lane & 31;   // point within wave

    __bf16* W1p = smem + 4*32*XSTR;           // [out 64][in 64] stride 72
    __bf16* W2p = W1p + 64*XSTR;              // [out 16][in 64] stride 72
    __bf16* Xw  = smem + wid*32*XSTR;         // per-wave [pt 32][feat 64] stride 72

    // stage weights (transposed to [out][in]) + biases
    for (int idx = tid; idx < 4096; idx += 256)
        W1p[(idx & 63)*XSTR + (idx >> 6)] = (__bf16)fc_w1[idx];
    for (int idx = tid; idx < 1024; idx += 256)
        W2p[(idx & 15)*XSTR + (idx >> 4)] = (__bf16)fc_w2[idx];
    if (tid < 64) b1lds[tid] = fc_b1[tid];
    if (tid < 16) b2lds[tid] = fc_b2[tid];
    __syncthreads();

    floatx4 b1v[4];
    #pragma unroll
    for (int mt = 0; mt < 4; ++mt)
        b1v[mt] = *(const floatx4*)(b1lds + mt*16 + quad*4);
    floatx4 b2v = *(const floatx4*)(b2lds + quad*4);

    int nb = (n + 127) >> 7;   // 128 points per block-iteration
    for (int batch = blockIdx.x; batch < nb; batch += (int)gridDim.x) {
        int ibase = batch*128 + wid*32;
        int pi = min(ibase + p32, n - 1);

        // ---- encoder for (point p32, pass hp) ----
        float2 xy = hp ? dir_[pi] : pos[pi];
        float hh[4];
        #pragma unroll
        for (int k = 0; k < 4; ++k)
            hh[k] = fast_tanh(xy.x*enc_w1[k] + xy.y*enc_w1[4+k] + enc_b1[k]);
        float e0 = enc_b2[0], e1 = enc_b2[1];
        #pragma unroll
        for (int k = 0; k < 4; ++k) {
            e0 += hh[k]*enc_w2[3*k + 0];
            e1 += hh[k]*enc_w2[3*k + 1];
        }
        float x = sigmoidf_(e0) * 255.0f;
        float y = sigmoidf_(e1) * 255.0f;
        int x0 = (int)x, y0 = (int)y;
        float xf = x - (float)x0, yf = y - (float)y0;
        int x1 = min(x0 + 1, 255), y1 = min(y0 + 1, 255);
        float oxf = 1.0f - xf, oyf = 1.0f - yf;
        float wtl = oyf*oxf, wtr = oyf*xf, wbl = yf*oxf, wbr = yf*xf;
        int ctl = ((y0 << 8) + x0) << 5, ctr = ((y0 << 8) + x1) << 5;
        int cbl = ((y1 << 8) + x0) << 5, cbr = ((y1 << 8) + x1) << 5;

        // ---- gather + blend 32 feats, write to Xw[p32][hp*32 ..] ----
        if (BF16G) {
            const __bf16* g = hp ? dir_gridb : pos_gridb;
            #pragma unroll
            for (int c = 0; c < 4; ++c) {
                bf16x8 a  = *(const bf16x8*)(g + ctl + c*8);
                bf16x8 b  = *(const bf16x8*)(g + ctr + c*8);
                bf16x8 cc = *(const bf16x8*)(g + cbl + c*8);
                bf16x8 d  = *(const bf16x8*)(g + cbr + c*8);
                bf16x8 r;
                #pragma unroll
                for (int j = 0; j < 8; ++j) {
                    float v = wtl*(float)a[j] + wtr*(float)b[j] + wbl*(float)cc[j] + wbr*(float)d[j];
                    r[j] = (__bf16)v;
                }
                *(bf16x8*)(Xw + p32*XSTR + hp*32 + c*8) = r;
            }
        } else {
            const float* g = hp ? dir_gridf : pos_gridf;
            #pragma unroll
            for (int c = 0; c < 4; ++c) {
                float fa[8], fb[8], fcc[8], fd[8];
                *(float4*)(fa)      = *(const float4*)(g + ctl + c*8);
                *(float4*)(fa + 4)  = *(const float4*)(g + ctl + c*8 + 4);
                *(float4*)(fb)      = *(const float4*)(g + ctr + c*8);
                *(float4*)(fb + 4)  = *(const float4*)(g + ctr + c*8 + 4);
                *(float4*)(fcc)     = *(const float4*)(g + cbl + c*8);
                *(float4*)(fcc + 4) = *(const float4*)(g + cbl + c*8 + 4);
                *(float4*)(fd)      = *(const float4*)(g + cbr + c*8);
                *(float4*)(fd + 4)  = *(const float4*)(g + cbr + c*8 + 4);
                bf16x8 r;
                #pragma unroll
                for (int j = 0; j < 8; ++j) {
                    float v = wtl*fa[j] + wtr*fb[j] + wbl*fcc[j] + wbr*fd[j];
                    r[j] = (__bf16)v;
                }
                *(bf16x8*)(Xw + p32*XSTR + hp*32 + c*8) = r;
            }
        }

        __asm__ volatile("s_waitcnt lgkmcnt(0)" ::: "memory");

        // ---- fc1: D[out 64][pt 32] = W1 * X^T : 16 MFMAs ----
        floatx4 acc[4][2];
        #pragma unroll
        for (int mt = 0; mt < 4; ++mt)
            #pragma unroll
            for (int nt = 0; nt < 2; ++nt)
                acc[mt][nt] = (floatx4){0.f, 0.f, 0.f, 0.f};

        bf16x8 wf[4][2], xfr[2][2];
        #pragma unroll
        for (int mt = 0; mt < 4; ++mt)
            #pragma unroll
            for (int ks = 0; ks < 2; ++ks)
                wf[mt][ks] = *(const bf16x8*)(W1p + (mt*16 + l15)*XSTR + ks*32 + quad*8);
        #pragma unroll
        for (int nt = 0; nt < 2; ++nt)
            #pragma unroll
            for (int ks = 0; ks < 2; ++ks)
                xfr[nt][ks] = *(const bf16x8*)(Xw + (nt*16 + l15)*XSTR + ks*32 + quad*8);
        #pragma unroll
        for (int ks = 0; ks < 2; ++ks)
            #pragma unroll
            for (int mt = 0; mt < 4; ++mt)
                #pragma unroll
                for (int nt = 0; nt < 2; ++nt)
                    acc[mt][nt] = __builtin_amdgcn_mfma_f32_16x16x32_bf16(wf[mt][ks], xfr[nt][ks], acc[mt][nt], 0, 0, 0);

        // writeback h1: lane holds feats mt*16+quad*4+r of point nt*16+l15 -> b64 stores
        #pragma unroll
        for (int mt = 0; mt < 4; ++mt)
            #pragma unroll
            for (int nt = 0; nt < 2; ++nt) {
                bf16x4 hv;
                #pragma unroll
                for (int r = 0; r < 4; ++r)
                    hv[r] = (__bf16)leaky(acc[mt][nt][r] + b1v[mt][r]);
                *(bf16x4*)(Xw + (nt*16 + l15)*XSTR + mt*16 + quad*4) = hv;
            }
        __asm__ volatile("s_waitcnt lgkmcnt(0)" ::: "memory");

        // ---- fc2: D[out 16][pt 32] = W2 * h1^T : 4 MFMAs ----
        floatx4 acc2[2];
        acc2[0] = (floatx4){0.f, 0.f, 0.f, 0.f};
        acc2[1] = (floatx4){0.f, 0.f, 0.f, 0.f};
        bf16x8 w2f[2], hfr[2][2];
        #pragma unroll
        for (int ks = 0; ks < 2; ++ks)
            w2f[ks] = *(const bf16x8*)(W2p + l15*XSTR + ks*32 + quad*8);
        #pragma unroll
        for (int nt = 0; nt < 2; ++nt)
            #pragma unroll
            for (int ks = 0; ks < 2; ++ks)
                hfr[nt][ks] = *(const bf16x8*)(Xw + (nt*16 + l15)*XSTR + ks*32 + quad*8);
        #pragma unroll
        for (int ks = 0; ks < 2; ++ks)
            #pragma unroll
            for (int nt = 0; nt < 2; ++nt)
                acc2[nt] = __builtin_amdgcn_mfma_f32_16x16x32_bf16(w2f[ks], hfr[nt][ks], acc2[nt], 0, 0, 0);

        // writeback h2 (fp32, [pt][16] stride 20): lane holds outs quad*4+r of pt nt*16+l15
        float* H2f = (float*)Xw;
        #pragma unroll
        for (int nt = 0; nt < 2; ++nt) {
            floatx4 hv;
            #pragma unroll
            for (int r = 0; r < 4; ++r)
                hv[r] = leaky(acc2[nt][r] + b2v[r]);
            *(floatx4*)(H2f + (nt*16 + l15)*20 + quad*4) = hv;
        }
        __asm__ volatile("s_waitcnt lgkmcnt(0)" ::: "memory");

        // ---- fc3/fc4 per-lane for pt=p32 (lane pairs duplicate; hp==0 stores) ----
        float h2[16];
        #pragma unroll
        for (int c = 0; c < 4; ++c) {
            floatx4 v = *(const floatx4*)(H2f + p32*20 + c*4);
            h2[4*c+0] = v[0]; h2[4*c+1] = v[1]; h2[4*c+2] = v[2]; h2[4*c+3] = v[3];
        }
        float h3[8];
        #pragma unroll
        for (int j = 0; j < 8; ++j) h3[j] = fc_b3[j];
        #pragma unroll
        for (int k = 0; k < 16; ++k) {
            float xv = h2[k];
            #pragma unroll
            for (int j = 0; j < 8; ++j) h3[j] = fmaf(xv, fc_w3[(k << 3) + j], h3[j]);
        }
        #pragma unroll
        for (int j = 0; j < 8; ++j) h3[j] = leaky(h3[j]);

        float o[3];
        #pragma unroll
        for (int j = 0; j < 3; ++j) o[j] = fc_b4[j];
        #pragma unroll
        for (int k = 0; k < 8; ++k) {
            float xv = h3[k];
            #pragma unroll
            for (int j = 0; j < 3; ++j) o[j] = fmaf(xv, fc_w4[3*k + j], o[j]);
        }
        int gi = ibase + p32;
        if (hp == 0 && gi < n) {
            #pragma unroll
            for (int j = 0; j < 3; ++j)
                out[3*gi + j] = sigmoidf_(leaky(o[j])) * 255.0f;
        }
    }
}

extern "C" void kernel_launch(void* const* d_in, const int* in_sizes, int n_in,
                              void* d_out, int out_size, void* d_ws, size_t ws_size,
                              hipStream_t stream) {
    int n = in_sizes[0] / 2;  // pos is [N,2]
    const int GELEMS = 256 * 256 * 32;
    bool use_bf16 = ws_size >= (size_t)(2 * GELEMS * sizeof(__bf16));
    __bf16* g0 = (__bf16*)d_ws;
    __bf16* g1 = g0 + GELEMS;

    if (use_bf16) {
        int total = 2 * (GELEMS / 4);
        convert_grids<<<(total + 255) / 256, 256, 0, stream>>>(
            (const float*)d_in[2], (const float*)d_in[3], g0, g1, GELEMS);
    }

    int nb = (n + 127) / 128;
    int blocks = nb < 2560 ? nb : 2560;
    if (use_bf16) {
        gridnet_fwd<true><<<blocks, 256, 0, stream>>>(
            (const float2*)d_in[0], (const float2*)d_in[1],
            (const float*)d_in[2], (const float*)d_in[3], g0, g1,
            (const float*)d_in[4], (const float*)d_in[5],
            (const float*)d_in[6], (const float*)d_in[7],
            (const float*)d_in[8], (const float*)d_in[9],
            (const float*)d_in[10], (const float*)d_in[11],
            (const float*)d_in[12], (const float*)d_in[13],
            (const float*)d_in[14], (const float*)d_in[15],
            (float*)d_out, n);
    } else {
        gridnet_fwd<false><<<blocks, 256, 0, stream>>>(
            (const float2*)d_in[0], (const float2*)d_in[1],
            (const float*)d_in[2], (const float*)d_in[3], g0, g1,
            (const float*)d_in[4], (const float*)d_in[5],
            (const float*)d_in[6], (const float*)d_in[7],
            (const float*)d_in[8], (const float*)d_in[9],
            (const float*)d_in[10], (const float*)d_in[11],
            (const float*)d_in[12], (const float*)d_in[13],
            (const float*)d_in[14], (const float*)d_in[15],
            (float*)d_out, n);
    }
}

// Round 4
// 238.969 us; speedup vs baseline: 1.2353x; 1.2353x over previous
//
#include <hip/hip_runtime.h>
#include <math.h>

typedef __attribute__((ext_vector_type(8))) __bf16 bf16x8;
typedef __attribute__((ext_vector_type(4))) __bf16 bf16x4;
typedef __attribute__((ext_vector_type(4))) float floatx4;
typedef __attribute__((ext_vector_type(8))) float floatx8;

__device__ __forceinline__ float fast_rcp(float x) { return __builtin_amdgcn_rcpf(x); }
__device__ __forceinline__ float sigmoidf_(float z) { return fast_rcp(1.0f + __expf(-z)); }
__device__ __forceinline__ float fast_tanh(float z) {
    float e = __expf(2.0f * z);
    return 1.0f - 2.0f * fast_rcp(e + 1.0f);
}
__device__ __forceinline__ float leaky(float v) { return fmaxf(v, 0.01f * v); }

// ---- grid fp32 -> bf16 conversion into workspace ----
__global__ void convert_grids(const float* __restrict__ g0, const float* __restrict__ g1,
                              __bf16* __restrict__ o0, __bf16* __restrict__ o1, int elems) {
    int i = blockIdx.x * blockDim.x + threadIdx.x;
    int nvec = elems >> 2;
    if (i < nvec) {
        float4 v = ((const float4*)g0)[i];
        bf16x4 r = { (__bf16)v.x, (__bf16)v.y, (__bf16)v.z, (__bf16)v.w };
        ((bf16x4*)o0)[i] = r;
    } else if (i < 2 * nvec) {
        int j = i - nvec;
        float4 v = ((const float4*)g1)[j];
        bf16x4 r = { (__bf16)v.x, (__bf16)v.y, (__bf16)v.z, (__bf16)v.w };
        ((bf16x4*)o1)[j] = r;
    }
}

#define XSTR 72   // X/h1 row stride in bf16 elems (144 B; 16B-aligned rows)

// 64 points per wave, lane = point (both passes per lane -> no tail duplication).
// fc1: D[out64][pt64] = W1[out][k] * X[pt][k]^T  (A=W1, B=X) -> 32 MFMAs.
// fc2: D[out16][pt64] -> 8 MFMAs. Writebacks are vectorized (b64 / b128).
// launch_bounds(256,3): VGPR cap ~170 so all 16 corner-chunk loads of a pass
// stay in flight (scatter-latency hiding), LDS 48.7KB -> 3 blocks/CU.
template<bool BF16G>
__global__ __launch_bounds__(256, 3) void gridnet_fwd(
    const float2* __restrict__ pos, const float2* __restrict__ dir_,
    const float* __restrict__ pos_gridf, const float* __restrict__ dir_gridf,
    const __bf16* __restrict__ pos_gridb, const __bf16* __restrict__ dir_gridb,
    const float* __restrict__ enc_w1, const float* __restrict__ enc_b1,
    const float* __restrict__ enc_w2, const float* __restrict__ enc_b2,
    const float* __restrict__ fc_w1, const float* __restrict__ fc_b1,
    const float* __restrict__ fc_w2, const float* __restrict__ fc_b2,
    const float* __restrict__ fc_w3, const float* __restrict__ fc_b3,
    const float* __restrict__ fc_w4, const float* __restrict__ fc_b4,
    float* __restrict__ out, int n)
{
    __shared__ __align__(16) __bf16 smem[4*64*XSTR + 64*XSTR + 16*XSTR];
    __shared__ float b1lds[64];
    __shared__ float b2lds[16];

    const int tid  = threadIdx.x;
    const int lane = tid & 63;
    const int wid  = tid >> 6;
    const int quad = lane >> 4;
    const int l15  = lane & 15;

    __bf16* W1p = smem + 4*64*XSTR;      // [out 64][in 64] stride 72
    __bf16* W2p = W1p + 64*XSTR;         // [out 16][in 64] stride 72
    __bf16* Xw  = smem + wid*64*XSTR;    // per-wave [pt 64][feat 64] stride 72

    for (int idx = tid; idx < 4096; idx += 256)
        W1p[(idx & 63)*XSTR + (idx >> 6)] = (__bf16)fc_w1[idx];
    for (int idx = tid; idx < 1024; idx += 256)
        W2p[(idx & 15)*XSTR + (idx >> 4)] = (__bf16)fc_w2[idx];
    if (tid < 64) b1lds[tid] = fc_b1[tid];
    if (tid < 16) b2lds[tid] = fc_b2[tid];
    __syncthreads();

    floatx4 b1v[4];
    #pragma unroll
    for (int mt = 0; mt < 4; ++mt)
        b1v[mt] = *(const floatx4*)(b1lds + mt*16 + quad*4);
    floatx4 b2v = *(const floatx4*)(b2lds + quad*4);

    int i  = blockIdx.x*256 + wid*64 + lane;
    int ic = min(i, n - 1);

    // ---- encoders for both passes up front ----
    int   ctl[2], ctr[2], cbl[2], cbr[2];
    float wtl[2], wtr[2], wbl[2], wbr[2];
    #pragma unroll
    for (int pass = 0; pass < 2; ++pass) {
        float2 xy = pass ? dir_[ic] : pos[ic];
        float hh[4];
        #pragma unroll
        for (int k = 0; k < 4; ++k)
            hh[k] = fast_tanh(xy.x*enc_w1[k] + xy.y*enc_w1[4+k] + enc_b1[k]);
        float e0 = enc_b2[0], e1 = enc_b2[1];
        #pragma unroll
        for (int k = 0; k < 4; ++k) {
            e0 += hh[k]*enc_w2[3*k + 0];
            e1 += hh[k]*enc_w2[3*k + 1];
        }
        float x = sigmoidf_(e0) * 255.0f;
        float y = sigmoidf_(e1) * 255.0f;
        int x0 = (int)x, y0 = (int)y;
        float xf = x - (float)x0, yf = y - (float)y0;
        int x1 = min(x0 + 1, 255), y1 = min(y0 + 1, 255);
        float oxf = 1.0f - xf, oyf = 1.0f - yf;
        wtl[pass] = oyf*oxf; wtr[pass] = oyf*xf;
        wbl[pass] = yf*oxf;  wbr[pass] = yf*xf;
        ctl[pass] = ((y0 << 8) + x0) << 5; ctr[pass] = ((y0 << 8) + x1) << 5;
        cbl[pass] = ((y1 << 8) + x0) << 5; cbr[pass] = ((y1 << 8) + x1) << 5;
    }

    // ---- gather + blend; all 16 chunk loads of a pass issued before blending ----
    #pragma unroll
    for (int pass = 0; pass < 2; ++pass) {
        if (BF16G) {
            const __bf16* g = pass ? dir_gridb : pos_gridb;
            bf16x8 A[4], B[4], C[4], D[4];
            #pragma unroll
            for (int c = 0; c < 4; ++c) A[c] = *(const bf16x8*)(g + ctl[pass] + c*8);
            #pragma unroll
            for (int c = 0; c < 4; ++c) B[c] = *(const bf16x8*)(g + ctr[pass] + c*8);
            #pragma unroll
            for (int c = 0; c < 4; ++c) C[c] = *(const bf16x8*)(g + cbl[pass] + c*8);
            #pragma unroll
            for (int c = 0; c < 4; ++c) D[c] = *(const bf16x8*)(g + cbr[pass] + c*8);
            #pragma unroll
            for (int c = 0; c < 4; ++c) {
                floatx8 r = wtl[pass]*__builtin_convertvector(A[c], floatx8)
                          + wtr[pass]*__builtin_convertvector(B[c], floatx8)
                          + wbl[pass]*__builtin_convertvector(C[c], floatx8)
                          + wbr[pass]*__builtin_convertvector(D[c], floatx8);
                *(bf16x8*)(Xw + lane*XSTR + pass*32 + c*8) = __builtin_convertvector(r, bf16x8);
            }
        } else {
            const float* g = pass ? dir_gridf : pos_gridf;
            #pragma unroll
            for (int c = 0; c < 4; ++c) {
                floatx8 fa = *(const floatx8*)(g + ctl[pass] + c*8);
                floatx8 fb = *(const floatx8*)(g + ctr[pass] + c*8);
                floatx8 fc = *(const floatx8*)(g + cbl[pass] + c*8);
                floatx8 fd = *(const floatx8*)(g + cbr[pass] + c*8);
                floatx8 r = wtl[pass]*fa + wtr[pass]*fb + wbl[pass]*fc + wbr[pass]*fd;
                *(bf16x8*)(Xw + lane*XSTR + pass*32 + c*8) = __builtin_convertvector(r, bf16x8);
            }
        }
    }

    __asm__ volatile("s_waitcnt lgkmcnt(0)" ::: "memory");

    // ---- fc1: D[out 64][pt 64] = W1 * X^T : 32 MFMAs, bias pre-loaded ----
    floatx4 acc[4][4];
    #pragma unroll
    for (int mt = 0; mt < 4; ++mt)
        #pragma unroll
        for (int nt = 0; nt < 4; ++nt)
            acc[mt][nt] = b1v[mt];

    #pragma unroll
    for (int ks = 0; ks < 2; ++ks) {
        bf16x8 wf[4], xf[4];
        #pragma unroll
        for (int mt = 0; mt < 4; ++mt)
            wf[mt] = *(const bf16x8*)(W1p + (mt*16 + l15)*XSTR + ks*32 + quad*8);
        #pragma unroll
        for (int nt = 0; nt < 4; ++nt)
            xf[nt] = *(const bf16x8*)(Xw + (nt*16 + l15)*XSTR + ks*32 + quad*8);
        #pragma unroll
        for (int mt = 0; mt < 4; ++mt)
            #pragma unroll
            for (int nt = 0; nt < 4; ++nt)
                acc[mt][nt] = __builtin_amdgcn_mfma_f32_16x16x32_bf16(wf[mt], xf[nt], acc[mt][nt], 0, 0, 0);
    }

    // writeback h1: lane holds feats (mt*16+quad*4 .. +3) of pt (nt*16+l15) -> b64 stores
    #pragma unroll
    for (int mt = 0; mt < 4; ++mt)
        #pragma unroll
        for (int nt = 0; nt < 4; ++nt) {
            bf16x4 hv;
            #pragma unroll
            for (int r = 0; r < 4; ++r)
                hv[r] = (__bf16)leaky(acc[mt][nt][r]);
            *(bf16x4*)(Xw + (nt*16 + l15)*XSTR + mt*16 + quad*4) = hv;
        }
    __asm__ volatile("s_waitcnt lgkmcnt(0)" ::: "memory");

    // ---- fc2: D[out 16][pt 64] : 8 MFMAs ----
    floatx4 acc2[4];
    #pragma unroll
    for (int nt = 0; nt < 4; ++nt) acc2[nt] = b2v;
    #pragma unroll
    for (int ks = 0; ks < 2; ++ks) {
        bf16x8 w2f = *(const bf16x8*)(W2p + l15*XSTR + ks*32 + quad*8);
        #pragma unroll
        for (int nt = 0; nt < 4; ++nt) {
            bf16x8 hf = *(const bf16x8*)(Xw + (nt*16 + l15)*XSTR + ks*32 + quad*8);
            acc2[nt] = __builtin_amdgcn_mfma_f32_16x16x32_bf16(w2f, hf, acc2[nt], 0, 0, 0);
        }
    }

    // writeback h2 fp32 [pt][16] stride 20 -> b128 stores
    float* H2f = (float*)Xw;
    #pragma unroll
    for (int nt = 0; nt < 4; ++nt) {
        floatx4 hv;
        #pragma unroll
        for (int r = 0; r < 4; ++r)
            hv[r] = leaky(acc2[nt][r]);
        *(floatx4*)(H2f + (nt*16 + l15)*20 + quad*4) = hv;
    }
    __asm__ volatile("s_waitcnt lgkmcnt(0)" ::: "memory");

    // ---- fc3/fc4 per lane (lane = point), sigmoid, store ----
    float h2[16];
    #pragma unroll
    for (int c = 0; c < 4; ++c) {
        floatx4 v = *(const floatx4*)(H2f + lane*20 + c*4);
        h2[4*c+0] = v[0]; h2[4*c+1] = v[1]; h2[4*c+2] = v[2]; h2[4*c+3] = v[3];
    }
    float h3[8];
    #pragma unroll
    for (int j = 0; j < 8; ++j) h3[j] = fc_b3[j];
    #pragma unroll
    for (int k = 0; k < 16; ++k) {
        float xv = h2[k];
        #pragma unroll
        for (int j = 0; j < 8; ++j) h3[j] = fmaf(xv, fc_w3[(k << 3) + j], h3[j]);
    }
    #pragma unroll
    for (int j = 0; j < 8; ++j) h3[j] = leaky(h3[j]);

    float o[3];
    #pragma unroll
    for (int j = 0; j < 3; ++j) o[j] = fc_b4[j];
    #pragma unroll
    for (int k = 0; k < 8; ++k) {
        float xv = h3[k];
        #pragma unroll
        for (int j = 0; j < 3; ++j) o[j] = fmaf(xv, fc_w4[3*k + j], o[j]);
    }
    if (i < n) {
        #pragma unroll
        for (int j = 0; j < 3; ++j)
            out[3*i + j] = sigmoidf_(leaky(o[j])) * 255.0f;
    }
}

extern "C" void kernel_launch(void* const* d_in, const int* in_sizes, int n_in,
                              void* d_out, int out_size, void* d_ws, size_t ws_size,
                              hipStream_t stream) {
    int n = in_sizes[0] / 2;  // pos is [N,2]
    const int GELEMS = 256 * 256 * 32;
    bool use_bf16 = ws_size >= (size_t)(2 * GELEMS * sizeof(__bf16));
    __bf16* g0 = (__bf16*)d_ws;
    __bf16* g1 = g0 + GELEMS;

    if (use_bf16) {
        int total = 2 * (GELEMS / 4);
        convert_grids<<<(total + 255) / 256, 256, 0, stream>>>(
            (const float*)d_in[2], (const float*)d_in[3], g0, g1, GELEMS);
    }

    int blocks = (n + 255) / 256;
    if (use_bf16) {
        gridnet_fwd<true><<<blocks, 256, 0, stream>>>(
            (const float2*)d_in[0], (const float2*)d_in[1],
            (const float*)d_in[2], (const float*)d_in[3], g0, g1,
            (const float*)d_in[4], (const float*)d_in[5],
            (const float*)d_in[6], (const float*)d_in[7],
            (const float*)d_in[8], (const float*)d_in[9],
            (const float*)d_in[10], (const float*)d_in[11],
            (const float*)d_in[12], (const float*)d_in[13],
            (const float*)d_in[14], (const float*)d_in[15],
            (float*)d_out, n);
    } else {
        gridnet_fwd<false><<<blocks, 256, 0, stream>>>(
            (const float2*)d_in[0], (const float2*)d_in[1],
            (const float*)d_in[2], (const float*)d_in[3], g0, g1,
            (const float*)d_in[4], (const float*)d_in[5],
            (const float*)d_in[6], (const float*)d_in[7],
            (const float*)d_in[8], (const float*)d_in[9],
            (const float*)d_in[10], (const float*)d_in[11],
            (const float*)d_in[12], (const float*)d_in[13],
            (const float*)d_in[14], (const float*)d_in[15],
            (float*)d_out, n);
    }
}